// Round 16
// baseline (488.727 us; speedup 1.0000x reference)
//
#include <hip/hip_runtime.h>
#include <hip/hip_bf16.h>
#include <hip/hip_cooperative_groups.h>

namespace cg = cooperative_groups;

#define G    128
#define MDIM 512
#define NDIM 512
#define DDIM 512
#define NORMC 0.0009765625f   // 1/(M+N)
#define BINW  0.5f            // NORMC * 512
#define PW   516              // P row width (f32)

using short8 = __attribute__((ext_vector_type(8))) short;
using short4v = __attribute__((ext_vector_type(4))) short;
using f32x4 = __attribute__((ext_vector_type(4))) float;

__device__ inline float bf2f(unsigned short u) {
    unsigned int x = ((unsigned int)u) << 16;
    return __builtin_bit_cast(float, x);
}
__device__ inline unsigned short f2bf(float f) {
    return __builtin_bit_cast(unsigned short, __float2bfloat16(f));
}
__device__ inline short4v cvt4(float4 f) {
    short4v r;
    r[0] = __builtin_bit_cast(short, __float2bfloat16(f.x));
    r[1] = __builtin_bit_cast(short, __float2bfloat16(f.y));
    r[2] = __builtin_bit_cast(short, __float2bfloat16(f.z));
    r[3] = __builtin_bit_cast(short, __float2bfloat16(f.w));
    return r;
}
// fp8 e4m3 (OCP, bias 7): valid for f in [2^-6, 448), positive, normal — ours is [0.38, 2.64].
__device__ inline unsigned char f2e4m3(float f) {
    unsigned int b = __builtin_bit_cast(unsigned int, f);
    unsigned int t = b + 0x7FFFFu + ((b >> 20) & 1u);   // RNE on dropped 20 bits
    return (unsigned char)((t >> 20) - 960u);            // 960 = 120<<3
}
__device__ inline float e4m32f(unsigned int u) {         // u = byte (sign 0)
    return __builtin_bit_cast(float, (u << 20) + 0x3C000000u);  // +120<<23
}

// ---------- Kernel 0 (fast path): normalize rows + cast to bf16 (round-11 version) ----------
__global__ __launch_bounds__(256)
void gt_cvt_kernel(const float* __restrict__ tra, const float* __restrict__ det,
                   unsigned short* __restrict__ trab, unsigned short* __restrict__ detb)
{
    int wave = threadIdx.x >> 6, lane = threadIdx.x & 63;
    long row0 = (long)blockIdx.x * 8 + wave * 2;       // even; 0 .. 2*G*512-2
    const long per = (long)G * MDIM;                   // 65536 (even) -> no straddle
    const float* src; unsigned short* dst; long r0;
    if (row0 < per) { src = tra; dst = trab; r0 = row0; }
    else            { src = det; dst = detb; r0 = row0 - per; }
    const float4* p0 = reinterpret_cast<const float4*>(src + r0 * DDIM);
    const float4* p1 = reinterpret_cast<const float4*>(src + (r0 + 1) * DDIM);
    float4 a0 = p0[lane * 2], a1 = p0[lane * 2 + 1];
    float4 b0 = p1[lane * 2], b1 = p1[lane * 2 + 1];
    float sa = a0.x*a0.x + a0.y*a0.y + a0.z*a0.z + a0.w*a0.w
             + a1.x*a1.x + a1.y*a1.y + a1.z*a1.z + a1.w*a1.w;
    float sb = b0.x*b0.x + b0.y*b0.y + b0.z*b0.z + b0.w*b0.w
             + b1.x*b1.x + b1.y*b1.y + b1.z*b1.z + b1.w*b1.w;
    #pragma unroll
    for (int off = 1; off < 64; off <<= 1) {
        sa += __shfl_xor(sa, off);
        sb += __shfl_xor(sb, off);
    }
    float ra = rsqrtf(sa), rb = rsqrtf(sb);
    short8 oa, ob;
    {
        short4v lo = cvt4(make_float4(a0.x*ra, a0.y*ra, a0.z*ra, a0.w*ra));
        short4v hi = cvt4(make_float4(a1.x*ra, a1.y*ra, a1.z*ra, a1.w*ra));
        oa[0]=lo[0]; oa[1]=lo[1]; oa[2]=lo[2]; oa[3]=lo[3];
        oa[4]=hi[0]; oa[5]=hi[1]; oa[6]=hi[2]; oa[7]=hi[3];
    }
    {
        short4v lo = cvt4(make_float4(b0.x*rb, b0.y*rb, b0.z*rb, b0.w*rb));
        short4v hi = cvt4(make_float4(b1.x*rb, b1.y*rb, b1.z*rb, b1.w*rb));
        ob[0]=lo[0]; ob[1]=lo[1]; ob[2]=lo[2]; ob[3]=lo[3];
        ob[4]=hi[0]; ob[5]=hi[1]; ob[6]=hi[2]; ob[7]=hi[3];
    }
    *reinterpret_cast<short8*>(dst + (size_t)r0 * 512 + lane * 8)       = oa;
    *reinterpret_cast<short8*>(dst + (size_t)(r0 + 1) * 512 + lane * 8) = ob;
}

// ---------- Kernel 1 (fast): bf16-input GEMM -> Kexp (fp8) + iter-0 column partials ----------
__global__ __launch_bounds__(256)
void gt_gemm_bf16(const unsigned short* __restrict__ trab, const unsigned short* __restrict__ detb,
                  const float* __restrict__ eps,
                  unsigned char* __restrict__ Ke, float* __restrict__ P1)
{
    __shared__ short As[128 * 40];
    __shared__ short Bs[128 * 40];
    int bid = blockIdx.x;
    int xcd = bid & 7, slot = bid >> 3;
    int g = xcd * 16 + (slot >> 4);
    int tile = slot & 15;
    int tm = tile >> 2, tn = tile & 3;
    int t = threadIdx.x, lane = t & 63, wave = t >> 6;
    int wr = wave >> 1, wc = wave & 1;
    f32x4 acc[4][4] = {};
    const unsigned short* Ab = trab + ((size_t)g << 18) + (size_t)(tm * 128) * 512;
    const unsigned short* Bb = detb + ((size_t)g << 18) + (size_t)(tn * 128) * 512;
    int srow = t >> 2;     // 0..63
    int sslot = t & 3;     // 16B slot within 32-elem K-chunk

    for (int kt = 0; kt < 16; ++kt) {
        int k0 = kt * 32;
        #pragma unroll
        for (int p = 0; p < 2; ++p) {
            int row = p * 64 + srow;
            short8 a = *reinterpret_cast<const short8*>(Ab + (size_t)row * 512 + k0 + sslot * 8);
            short8 b = *reinterpret_cast<const short8*>(Bb + (size_t)row * 512 + k0 + sslot * 8);
            *reinterpret_cast<short8*>(&As[row * 40 + sslot * 8]) = a;
            *reinterpret_cast<short8*>(&Bs[row * 40 + sslot * 8]) = b;
        }
        __syncthreads();
        short8 af[4], bfv[4];
        #pragma unroll
        for (int i = 0; i < 4; ++i) {
            int arow = wr * 64 + i * 16 + (lane & 15);
            af[i]  = *reinterpret_cast<const short8*>(&As[arow * 40 + (lane >> 4) * 8]);
            int brow = wc * 64 + i * 16 + (lane & 15);
            bfv[i] = *reinterpret_cast<const short8*>(&Bs[brow * 40 + (lane >> 4) * 8]);
        }
        #pragma unroll
        for (int i = 0; i < 4; ++i)
            #pragma unroll
            for (int j = 0; j < 4; ++j)
                acc[i][j] = __builtin_amdgcn_mfma_f32_16x16x32_bf16(af[i], bfv[j], acc[i][j], 0, 0, 0);
        __syncthreads();
    }

    float lam = __expf(eps[0]) + 0.03f;
    float nscale = -1.0f / lam;
    size_t kbase = (size_t)g << 18;   // bytes, 512*512 per graph
    int r0v = (lane >> 4) * 4;
    int c0 = lane & 15;
    #pragma unroll
    for (int j = 0; j < 4; ++j) {
        int lcol = wc * 64 + j * 16 + c0;
        int colg = tn * 128 + lcol;
        float cacc = 0.f;
        #pragma unroll
        for (int i = 0; i < 4; ++i) {
            int lrow = wr * 64 + i * 16 + r0v;
            #pragma unroll
            for (int r = 0; r < 4; ++r) {
                float ev = __expf(acc[i][j][r] * nscale);
                unsigned char q = f2e4m3(ev);
                Ke[kbase + (size_t)(tm * 128 + lrow + r) * 512 + colg] = q;
                cacc += e4m32f(q);     // colsum of the QUANTIZED K (consistent with iters)
            }
        }
        cacc += __shfl_down(cacc, 32);
        cacc += __shfl_down(cacc, 16);
        if (lane < 16)
            P1[(size_t)g * (8 * PW) + (size_t)(2 * tm + wr) * PW + tn * 128 + wc * 64 + j * 16 + lane] = cacc;
    }
}

// ---------- Legacy fused GEMM (slow/fallback path, f32 K into out) ----------
__global__ __launch_bounds__(256)
void gt_gemm_legacy(const float* __restrict__ tra, const float* __restrict__ det,
                    const float* __restrict__ eps,
                    float* __restrict__ Koutf, float* __restrict__ P1)
{
    __shared__ short As[128 * 40];
    __shared__ short Bs[128 * 40];
    __shared__ float rnA[128];
    __shared__ float rnB[128];
    int bid = blockIdx.x;
    int xcd = bid & 7, slot = bid >> 3;
    int g = xcd * 16 + (slot >> 4);
    int tile = slot & 15;
    int tm = tile >> 2, tn = tile & 3;
    int t = threadIdx.x, lane = t & 63, wave = t >> 6;
    int wr = wave >> 1, wc = wave & 1;
    f32x4 acc[4][4] = {};
    const float* Abase = tra + (size_t)g * MDIM * DDIM + (size_t)(tm * 128) * DDIM;
    const float* Bbase = det + (size_t)g * NDIM * DDIM + (size_t)(tn * 128) * DDIM;
    int srow = t >> 3, scol = t & 7;
    float ssA[4] = {0.f, 0.f, 0.f, 0.f};
    float ssB[4] = {0.f, 0.f, 0.f, 0.f};

    for (int kt = 0; kt < 16; ++kt) {
        int k0 = kt * 32;
        #pragma unroll
        for (int p = 0; p < 4; ++p) {
            int row = p * 32 + srow;
            float4 a = *reinterpret_cast<const float4*>(Abase + (size_t)row * DDIM + k0 + scol * 4);
            float4 b = *reinterpret_cast<const float4*>(Bbase + (size_t)row * DDIM + k0 + scol * 4);
            ssA[p] += a.x*a.x + a.y*a.y + a.z*a.z + a.w*a.w;
            ssB[p] += b.x*b.x + b.y*b.y + b.z*b.z + b.w*b.w;
            *reinterpret_cast<short4v*>(&As[row * 40 + scol * 4]) = cvt4(a);
            *reinterpret_cast<short4v*>(&Bs[row * 40 + scol * 4]) = cvt4(b);
        }
        __syncthreads();
        short8 af[4], bfv[4];
        #pragma unroll
        for (int i = 0; i < 4; ++i) {
            int arow = wr * 64 + i * 16 + (lane & 15);
            af[i]  = *reinterpret_cast<const short8*>(&As[arow * 40 + (lane >> 4) * 8]);
            int brow = wc * 64 + i * 16 + (lane & 15);
            bfv[i] = *reinterpret_cast<const short8*>(&Bs[brow * 40 + (lane >> 4) * 8]);
        }
        #pragma unroll
        for (int i = 0; i < 4; ++i)
            #pragma unroll
            for (int j = 0; j < 4; ++j)
                acc[i][j] = __builtin_amdgcn_mfma_f32_16x16x32_bf16(af[i], bfv[j], acc[i][j], 0, 0, 0);
        __syncthreads();
    }

    #pragma unroll
    for (int p = 0; p < 4; ++p) {
        float a = ssA[p], b = ssB[p];
        a += __shfl_xor(a, 1); a += __shfl_xor(a, 2); a += __shfl_xor(a, 4);
        b += __shfl_xor(b, 1); b += __shfl_xor(b, 2); b += __shfl_xor(b, 4);
        if (scol == 0) { rnA[p * 32 + srow] = rsqrtf(a); rnB[p * 32 + srow] = rsqrtf(b); }
    }
    __syncthreads();

    float lam = __expf(eps[0]) + 0.03f;
    float nscale = -1.0f / lam;
    size_t obase = (size_t)g * 263169;
    int r0v = (lane >> 4) * 4;
    int c0 = lane & 15;
    #pragma unroll
    for (int j = 0; j < 4; ++j) {
        int lcol = wc * 64 + j * 16 + c0;
        int colg = tn * 128 + lcol;
        float sc2 = nscale * rnB[lcol];
        float cacc = 0.f;
        #pragma unroll
        for (int i = 0; i < 4; ++i) {
            int lrow = wr * 64 + i * 16 + r0v;
            #pragma unroll
            for (int r = 0; r < 4; ++r) {
                float ev = __expf(acc[i][j][r] * rnA[lrow + r] * sc2);
                cacc += ev;
                int rowg = tm * 128 + lrow + r;
                Koutf[obase + (size_t)rowg * 513 + colg] = ev;
            }
        }
        cacc += __shfl_down(cacc, 32);
        cacc += __shfl_down(cacc, 16);
        if (lane < 16)
            P1[(size_t)g * (8 * PW) + (size_t)(2 * tm + wr) * PW + tn * 128 + wc * 64 + j * 16 + lane] = cacc;
    }
}

// ---------- Persistent cooperative Sinkhorn: K-half in LDS, 8 iters, 7 grid.syncs ----------
// 256 blocks x 512 threads, 1 block/CU (149.5 KB dynamic LDS). Block (g, b=half).
__global__ __launch_bounds__(512, 1)
void gt_sink_coop(const unsigned char* __restrict__ Ke,
                  const float* __restrict__ alpha, const float* __restrict__ eps,
                  const float* __restrict__ P1init, float* __restrict__ Pex,
                  float* __restrict__ outp)
{
    extern __shared__ char smem[];
    unsigned char* Ksh = (unsigned char*)smem;                       // 131072 B
    float* bv_s    = (float*)(smem + 131072);                        // 512
    float* colpart = bv_s + 512;                                     // 8*512
    float* rtmp    = colpart + 8 * 512;                              // 8
    float* scal    = rtmp + 8;                                       // 2

    cg::grid_group grid = cg::this_grid();
    int bid = blockIdx.x;
    int g = bid >> 1, b = bid & 1;
    int t = threadIdx.x, lane = t & 63, wv = t >> 6;
    float lam = __expf(eps[0]) + 0.03f;
    float val = __expf(-alpha[0] / lam);

    // Load this block's K half (rows b*256 .. b*256+255) into LDS, coalesced.
    {
        const uint4* src = reinterpret_cast<const uint4*>(Ke + ((size_t)g << 18) + ((size_t)b << 17));
        uint4* dst = reinterpret_cast<uint4*>(Ksh);
        #pragma unroll
        for (int i = 0; i < 16; ++i) dst[t + 512 * i] = src[t + 512 * i];
    }
    __syncthreads();

    float au512p = 1.0f;
    float* PexG = Pex + (size_t)g * (8 * PW);
    size_t obase = (size_t)g * 263169;

    for (int it = 0; it < 8; ++it) {
        // ---- head: bv_j from previous colsums ----
        float cs;
        if (it == 0) {
            const float* Pg = P1init + (size_t)g * (8 * PW);
            cs = 0.f;
            #pragma unroll
            for (int k8 = 0; k8 < 8; ++k8) cs += Pg[k8 * PW + t];
        } else {
            int pr = (it - 1) & 1;
            cs = PexG[(pr * 2 + 0) * PW + t] + PexG[(pr * 2 + 1) * PW + t];
        }
        float bvt = NORMC / (cs + val * au512p);
        bv_s[t] = bvt;
        float sbv = bvt;
        #pragma unroll
        for (int off = 1; off < 64; off <<= 1) sbv += __shfl_xor(sbv, off);
        if (lane == 0) rtmp[wv] = sbv;
        __syncthreads();
        if (t == 0) {
            float S_bv = 0.f;
            #pragma unroll
            for (int w = 0; w < 8; ++w) S_bv += rtmp[w];
            float Sau;
            if (it == 0) Sau = 513.f;
            else {
                int pr = (it - 1) & 1;
                Sau = PexG[(pr * 2 + 0) * PW + 512] + PexG[(pr * 2 + 1) * PW + 512] + au512p;
            }
            float bv512 = BINW / (val * Sau);
            scal[0] = bv512;
            scal[1] = BINW / (val * (S_bv + bv512));   // new au512
        }
        __syncthreads();
        float bv512 = scal[0];
        float au512n = scal[1];

        float bvr[8];
        #pragma unroll
        for (int k = 0; k < 8; ++k) bvr[k] = bv_s[lane * 8 + k];

        if (it < 7) {
            float colacc[8] = {};
            float suma = 0.f;
            for (int i = 0; i < 32; ++i) {
                int rl = wv + i * 8;
                uint2 w = *reinterpret_cast<const uint2*>(Ksh + rl * 512 + lane * 8);
                float kv[8];
                kv[0] = e4m32f(w.x & 255u);
                kv[1] = e4m32f((w.x >> 8) & 255u);
                kv[2] = e4m32f((w.x >> 16) & 255u);
                kv[3] = e4m32f(w.x >> 24);
                kv[4] = e4m32f(w.y & 255u);
                kv[5] = e4m32f((w.y >> 8) & 255u);
                kv[6] = e4m32f((w.y >> 16) & 255u);
                kv[7] = e4m32f(w.y >> 24);
                float dot = 0.f;
                #pragma unroll
                for (int k = 0; k < 8; ++k) dot += kv[k] * bvr[k];
                #pragma unroll
                for (int off = 1; off < 64; off <<= 1) dot += __shfl_xor(dot, off);
                float au_r = NORMC / (dot + val * bv512);
                suma += au_r;
                #pragma unroll
                for (int k = 0; k < 8; ++k) colacc[k] += kv[k] * au_r;
            }
            #pragma unroll
            for (int k = 0; k < 8; ++k) colpart[wv * 512 + lane * 8 + k] = colacc[k];
            if (lane == 0) rtmp[wv] = suma;
            __syncthreads();
            float* Pw = PexG + ((it & 1) * 2 + b) * PW;
            float s0 = 0.f;
            #pragma unroll
            for (int w = 0; w < 8; ++w) s0 += colpart[w * 512 + t];
            Pw[t] = s0;
            if (t == 0) {
                float ss = 0.f;
                #pragma unroll
                for (int w = 0; w < 8; ++w) ss += rtmp[w];
                Pw[512] = ss;
            }
            au512p = au512n;
            grid.sync();
        } else {
            // final iteration: u-step 8 + output write
            for (int i = 0; i < 32; ++i) {
                int rl = wv + i * 8;
                int r = b * 256 + rl;
                uint2 w = *reinterpret_cast<const uint2*>(Ksh + rl * 512 + lane * 8);
                float kv[8];
                kv[0] = e4m32f(w.x & 255u);
                kv[1] = e4m32f((w.x >> 8) & 255u);
                kv[2] = e4m32f((w.x >> 16) & 255u);
                kv[3] = e4m32f(w.x >> 24);
                kv[4] = e4m32f(w.y & 255u);
                kv[5] = e4m32f((w.y >> 8) & 255u);
                kv[6] = e4m32f((w.y >> 16) & 255u);
                kv[7] = e4m32f(w.y >> 24);
                float dot = 0.f;
                #pragma unroll
                for (int k = 0; k < 8; ++k) dot += kv[k] * bvr[k];
                #pragma unroll
                for (int off = 1; off < 64; off <<= 1) dot += __shfl_xor(dot, off);
                float au_r = NORMC / (dot + val * bv512);
                float* orow = outp + obase + (size_t)r * 513;
                f32x4 o0, o1;
                #pragma unroll
                for (int k = 0; k < 4; ++k) {
                    o0[k] = kv[k] * au_r * bvr[k];
                    o1[k] = kv[4 + k] * au_r * bvr[4 + k];
                }
                *reinterpret_cast<f32x4*>(orow + lane * 8)     = o0;
                *reinterpret_cast<f32x4*>(orow + lane * 8 + 4) = o1;
                if (lane == 0) orow[512] = val * au_r * bv512;
            }
            if (b == 1) {
                float* brow = outp + obase + (size_t)512 * 513;
                brow[t] = val * au512n * bv_s[t];
                if (t == 0) brow[512] = val * au512n * bv512;
            }
        }
    }
}

// ---------- Dispatch-loop iteration (round-11, fallback) ----------
template<bool FP8, bool LAST>
__global__ __launch_bounds__(512)
void gt_iter(const void* __restrict__ Kv,
             const float* __restrict__ alpha, const float* __restrict__ eps,
             const float* __restrict__ Pread, float* __restrict__ Pwrite,
             float* __restrict__ outp, int first, int writeP)
{
    __shared__ float bv_s[512];
    __shared__ float colpart[8][512];
    __shared__ float rtmp[8];
    __shared__ float scal[2];
    int g = blockIdx.y, rb = blockIdx.x;
    int t = threadIdx.x, lane = t & 63, wv = t >> 6;
    float lam = __expf(eps[0]) + 0.03f;
    float val = __expf(-alpha[0] / lam);
    const float* Pg = Pread + (size_t)g * (8 * PW);
    float au512p = first ? 1.0f : Pg[513];
    float cs = 0.f;
    #pragma unroll
    for (int b = 0; b < 8; ++b) cs += Pg[b * PW + t];
    float bvt = NORMC / (cs + val * au512p);
    bv_s[t] = bvt;
    float sb = bvt;
    #pragma unroll
    for (int off = 1; off < 64; off <<= 1) sb += __shfl_xor(sb, off);
    if (lane == 0) rtmp[wv] = sb;
    __syncthreads();
    if (t == 0) {
        float S_bv = 0.f;
        #pragma unroll
        for (int w = 0; w < 8; ++w) S_bv += rtmp[w];
        float S_au_prev;
        if (first) S_au_prev = 513.f;
        else { float s = 0.f; for (int b = 0; b < 8; ++b) s += Pg[b * PW + 512]; S_au_prev = s + au512p; }
        float bv512 = BINW / (val * S_au_prev);
        float au512n = BINW / (val * (S_bv + bv512));
        scal[0] = bv512;
        scal[1] = au512n;
        if (!LAST && rb == 0) Pwrite[(size_t)g * (8 * PW) + 513] = au512n;
    }
    __syncthreads();
    float bv512 = scal[0];

    float bvr[8];
    #pragma unroll
    for (int k = 0; k < 8; ++k) bvr[k] = bv_s[lane * 8 + k];
    float colacc[8] = {};
    float suma = 0.f;
    size_t base = FP8 ? ((size_t)g << 18) : ((size_t)g * 263169);
    size_t obase = (size_t)g * 263169;
    int rowbase = rb * 64;
    for (int rr = wv; rr < 64; rr += 8) {
        int r = rowbase + rr;
        float kv[8];
        if constexpr (FP8) {
            uint2 w = *reinterpret_cast<const uint2*>((const unsigned char*)Kv + base + (size_t)r * 512 + lane * 8);
            kv[0] = e4m32f(w.x & 255u);
            kv[1] = e4m32f((w.x >> 8) & 255u);
            kv[2] = e4m32f((w.x >> 16) & 255u);
            kv[3] = e4m32f(w.x >> 24);
            kv[4] = e4m32f(w.y & 255u);
            kv[5] = e4m32f((w.y >> 8) & 255u);
            kv[6] = e4m32f((w.y >> 16) & 255u);
            kv[7] = e4m32f(w.y >> 24);
        } else {
            const float* p = (const float*)Kv + base + (size_t)r * 513 + lane * 8;
            #pragma unroll
            for (int k = 0; k < 8; ++k) kv[k] = p[k];
        }
        float dot = 0.f;
        #pragma unroll
        for (int k = 0; k < 8; ++k) dot += kv[k] * bvr[k];
        #pragma unroll
        for (int off = 1; off < 64; off <<= 1) dot += __shfl_xor(dot, off);
        float au_r = NORMC / (dot + val * bv512);
        if constexpr (LAST) {
            float* orow = outp + obase + (size_t)r * 513;
            f32x4 o0, o1;
            #pragma unroll
            for (int k = 0; k < 4; ++k) {
                o0[k] = kv[k] * au_r * bvr[k];
                o1[k] = kv[4 + k] * au_r * bvr[4 + k];
            }
            *reinterpret_cast<f32x4*>(orow + lane * 8)     = o0;
            *reinterpret_cast<f32x4*>(orow + lane * 8 + 4) = o1;
            if (lane == 0) orow[512] = val * au_r * bv512;
        } else {
            suma += au_r;
            #pragma unroll
            for (int k = 0; k < 8; ++k) colacc[k] += kv[k] * au_r;
        }
    }
    if constexpr (LAST) {
        if (rb == 7) {
            float au512n = scal[1];
            float* brow = outp + obase + (size_t)512 * 513;
            brow[t] = val * au512n * bv_s[t];
            if (t == 0) brow[512] = val * au512n * bv512;
        }
    } else if (writeP) {
        #pragma unroll
        for (int k = 0; k < 8; ++k) colpart[wv][lane * 8 + k] = colacc[k];
        if (lane == 0) rtmp[wv] = suma;
        __syncthreads();
        float s0 = 0.f;
        #pragma unroll
        for (int w = 0; w < 8; ++w) s0 += colpart[w][t];
        float* Pw = Pwrite + (size_t)g * (8 * PW) + (size_t)rb * PW;
        Pw[t] = s0;
        if (t == 0) {
            float ss = 0.f;
            #pragma unroll
            for (int w = 0; w < 8; ++w) ss += rtmp[w];
            Pw[512] = ss;
        }
    }
}

extern "C" void kernel_launch(void* const* d_in, const int* in_sizes, int n_in,
                              void* d_out, int out_size, void* d_ws, size_t ws_size,
                              hipStream_t stream) {
    const float* det   = (const float*)d_in[0];
    const float* tra   = (const float*)d_in[1];
    const float* alpha = (const float*)d_in[2];
    const float* eps   = (const float*)d_in[3];
    float* out = (float*)d_out;

    float* P0 = (float*)d_ws;                       // G*8*PW f32 (also coop Pex)
    float* P1 = P0 + (size_t)G * 8 * PW;            // G*8*PW f32 (iter-0 partials)
    unsigned char* ke = (unsigned char*)(P1 + (size_t)G * 8 * PW);   // G*512*512 fp8

    size_t smallBytes = (size_t)2 * G * 8 * PW * 4;
    bool fast = ws_size >= smallBytes + ((size_t)G << 18);

    if (fast) {
        unsigned short* trab = (unsigned short*)out;
        unsigned short* detb = trab + ((size_t)G << 18);
        gt_cvt_kernel<<<(2 * G * MDIM) / 8, 256, 0, stream>>>(tra, det, trab, detb);
        gt_gemm_bf16<<<2048, 256, 0, stream>>>(trab, detb, eps, ke, P1);

        const unsigned int SMEM = 131072u + 512u * 4 + 8u * 512 * 4 + 8u * 4 + 2u * 4;
        bool coop_ok = false;
        if (hipFuncSetAttribute((const void*)gt_sink_coop,
                                hipFuncAttributeMaxDynamicSharedMemorySize,
                                (int)SMEM) == hipSuccess) {
            const unsigned char* keArg = ke;
            void* args[] = { (void*)&keArg, (void*)&alpha, (void*)&eps,
                             (void*)&P1, (void*)&P0, (void*)&out };
            if (hipLaunchCooperativeKernel((const void*)gt_sink_coop,
                                           dim3(256), dim3(512),
                                           args, SMEM, stream) == hipSuccess)
                coop_ok = true;
        }
        if (!coop_ok) {
            float* Pr = P1; float* Pw = P0;
            for (int it = 0; it < 7; ++it) {
                gt_iter<true, false><<<dim3(8, G), 512, 0, stream>>>((const void*)ke, alpha, eps, Pr, Pw, nullptr, it == 0 ? 1 : 0, 1);
                float* tmp = Pr; Pr = Pw; Pw = tmp;
            }
            gt_iter<true, true><<<dim3(8, G), 512, 0, stream>>>((const void*)ke, alpha, eps, Pr, Pw, out, 0, 0);
        }
    } else {
        gt_gemm_legacy<<<2048, 256, 0, stream>>>(tra, det, eps, out, P1);
        float* Pr = P1; float* Pw = P0;
        for (int it = 0; it < 7; ++it) {
            gt_iter<false, false><<<dim3(8, G), 512, 0, stream>>>((const void*)out, alpha, eps, Pr, Pw, nullptr, it == 0 ? 1 : 0, 1);
            float* tmp = Pr; Pr = Pw; Pw = tmp;
        }
        gt_iter<false, true><<<dim3(8, G), 512, 0, stream>>>((const void*)out, alpha, eps, Pr, Pw, out, 0, 0);
    }
}

// Round 17
// 273.072 us; speedup vs baseline: 1.7897x; 1.7897x over previous
//
#include <hip/hip_runtime.h>
#include <hip/hip_bf16.h>

#define G    128
#define MDIM 512
#define NDIM 512
#define DDIM 512
#define NORMC 0.0009765625f   // 1/(M+N)
#define BINW  0.5f            // NORMC * 512
#define PW   516              // P row width (f32): [0..511] colsums, [512] sum(au) partial, [513] au512

using short8 = __attribute__((ext_vector_type(8))) short;
using short4v = __attribute__((ext_vector_type(4))) short;
using f32x4 = __attribute__((ext_vector_type(4))) float;

__device__ inline float bf2f(unsigned short u) {
    unsigned int x = ((unsigned int)u) << 16;
    return __builtin_bit_cast(float, x);
}
__device__ inline unsigned short f2bf(float f) {
    return __builtin_bit_cast(unsigned short, __float2bfloat16(f));
}
__device__ inline short4v cvt4(float4 f) {
    short4v r;
    r[0] = __builtin_bit_cast(short, __float2bfloat16(f.x));
    r[1] = __builtin_bit_cast(short, __float2bfloat16(f.y));
    r[2] = __builtin_bit_cast(short, __float2bfloat16(f.z));
    r[3] = __builtin_bit_cast(short, __float2bfloat16(f.w));
    return r;
}
// fp8 e4m3 (OCP, bias 7): valid for f in [2^-6, 448), positive, normal — ours is [0.38, 2.64].
__device__ inline unsigned char f2e4m3(float f) {
    unsigned int b = __builtin_bit_cast(unsigned int, f);
    unsigned int t = b + 0x7FFFFu + ((b >> 20) & 1u);   // RNE on dropped 20 bits
    return (unsigned char)((t >> 20) - 960u);            // 960 = 120<<3
}
__device__ inline float e4m32f(unsigned int u) {         // u = byte (sign 0)
    return __builtin_bit_cast(float, (u << 20) + 0x3C000000u);  // +120<<23
}

// ---------- Kernel 0 (fast path): normalize rows + cast to bf16 ----------
__global__ __launch_bounds__(256)
void gt_cvt_kernel(const float* __restrict__ tra, const float* __restrict__ det,
                   unsigned short* __restrict__ trab, unsigned short* __restrict__ detb)
{
    int wave = threadIdx.x >> 6, lane = threadIdx.x & 63;
    long row0 = (long)blockIdx.x * 8 + wave * 2;       // even; 0 .. 2*G*512-2
    const long per = (long)G * MDIM;                   // 65536 (even) -> no straddle
    const float* src; unsigned short* dst; long r0;
    if (row0 < per) { src = tra; dst = trab; r0 = row0; }
    else            { src = det; dst = detb; r0 = row0 - per; }
    const float4* p0 = reinterpret_cast<const float4*>(src + r0 * DDIM);
    const float4* p1 = reinterpret_cast<const float4*>(src + (r0 + 1) * DDIM);
    float4 a0 = p0[lane * 2], a1 = p0[lane * 2 + 1];
    float4 b0 = p1[lane * 2], b1 = p1[lane * 2 + 1];
    float sa = a0.x*a0.x + a0.y*a0.y + a0.z*a0.z + a0.w*a0.w
             + a1.x*a1.x + a1.y*a1.y + a1.z*a1.z + a1.w*a1.w;
    float sb = b0.x*b0.x + b0.y*b0.y + b0.z*b0.z + b0.w*b0.w
             + b1.x*b1.x + b1.y*b1.y + b1.z*b1.z + b1.w*b1.w;
    #pragma unroll
    for (int off = 1; off < 64; off <<= 1) {
        sa += __shfl_xor(sa, off);
        sb += __shfl_xor(sb, off);
    }
    float ra = rsqrtf(sa), rb = rsqrtf(sb);
    short8 oa, ob;
    {
        short4v lo = cvt4(make_float4(a0.x*ra, a0.y*ra, a0.z*ra, a0.w*ra));
        short4v hi = cvt4(make_float4(a1.x*ra, a1.y*ra, a1.z*ra, a1.w*ra));
        oa[0]=lo[0]; oa[1]=lo[1]; oa[2]=lo[2]; oa[3]=lo[3];
        oa[4]=hi[0]; oa[5]=hi[1]; oa[6]=hi[2]; oa[7]=hi[3];
    }
    {
        short4v lo = cvt4(make_float4(b0.x*rb, b0.y*rb, b0.z*rb, b0.w*rb));
        short4v hi = cvt4(make_float4(b1.x*rb, b1.y*rb, b1.z*rb, b1.w*rb));
        ob[0]=lo[0]; ob[1]=lo[1]; ob[2]=lo[2]; ob[3]=lo[3];
        ob[4]=hi[0]; ob[5]=hi[1]; ob[6]=hi[2]; ob[7]=hi[3];
    }
    *reinterpret_cast<short8*>(dst + (size_t)r0 * 512 + lane * 8)       = oa;
    *reinterpret_cast<short8*>(dst + (size_t)(r0 + 1) * 512 + lane * 8) = ob;
}

// ---------- Kernel 1 (fast): bf16-input GEMM -> Kexp (fp8) + iter-0 column partials ----------
__global__ __launch_bounds__(256)
void gt_gemm_bf16(const unsigned short* __restrict__ trab, const unsigned short* __restrict__ detb,
                  const float* __restrict__ eps,
                  unsigned char* __restrict__ Ke, float* __restrict__ P1)
{
    __shared__ short As[128 * 40];
    __shared__ short Bs[128 * 40];
    int bid = blockIdx.x;
    int xcd = bid & 7, slot = bid >> 3;
    int g = xcd * 16 + (slot >> 4);
    int tile = slot & 15;
    int tm = tile >> 2, tn = tile & 3;
    int t = threadIdx.x, lane = t & 63, wave = t >> 6;
    int wr = wave >> 1, wc = wave & 1;
    f32x4 acc[4][4] = {};
    const unsigned short* Ab = trab + ((size_t)g << 18) + (size_t)(tm * 128) * 512;
    const unsigned short* Bb = detb + ((size_t)g << 18) + (size_t)(tn * 128) * 512;
    int srow = t >> 2;     // 0..63
    int sslot = t & 3;     // 16B slot within 32-elem K-chunk

    for (int kt = 0; kt < 16; ++kt) {
        int k0 = kt * 32;
        #pragma unroll
        for (int p = 0; p < 2; ++p) {
            int row = p * 64 + srow;
            short8 a = *reinterpret_cast<const short8*>(Ab + (size_t)row * 512 + k0 + sslot * 8);
            short8 b = *reinterpret_cast<const short8*>(Bb + (size_t)row * 512 + k0 + sslot * 8);
            *reinterpret_cast<short8*>(&As[row * 40 + sslot * 8]) = a;
            *reinterpret_cast<short8*>(&Bs[row * 40 + sslot * 8]) = b;
        }
        __syncthreads();
        short8 af[4], bfv[4];
        #pragma unroll
        for (int i = 0; i < 4; ++i) {
            int arow = wr * 64 + i * 16 + (lane & 15);
            af[i]  = *reinterpret_cast<const short8*>(&As[arow * 40 + (lane >> 4) * 8]);
            int brow = wc * 64 + i * 16 + (lane & 15);
            bfv[i] = *reinterpret_cast<const short8*>(&Bs[brow * 40 + (lane >> 4) * 8]);
        }
        #pragma unroll
        for (int i = 0; i < 4; ++i)
            #pragma unroll
            for (int j = 0; j < 4; ++j)
                acc[i][j] = __builtin_amdgcn_mfma_f32_16x16x32_bf16(af[i], bfv[j], acc[i][j], 0, 0, 0);
        __syncthreads();
    }

    float lam = __expf(eps[0]) + 0.03f;
    float nscale = -1.0f / lam;
    size_t kbase = (size_t)g << 18;   // bytes, 512*512 per graph
    int r0v = (lane >> 4) * 4;
    int c0 = lane & 15;
    #pragma unroll
    for (int j = 0; j < 4; ++j) {
        int lcol = wc * 64 + j * 16 + c0;
        int colg = tn * 128 + lcol;
        float cacc = 0.f;
        #pragma unroll
        for (int i = 0; i < 4; ++i) {
            int lrow = wr * 64 + i * 16 + r0v;
            #pragma unroll
            for (int r = 0; r < 4; ++r) {
                float ev = __expf(acc[i][j][r] * nscale);
                unsigned char q = f2e4m3(ev);
                Ke[kbase + (size_t)(tm * 128 + lrow + r) * 512 + colg] = q;
                cacc += e4m32f(q);     // colsum of the QUANTIZED K (consistent with iters)
            }
        }
        cacc += __shfl_down(cacc, 32);
        cacc += __shfl_down(cacc, 16);
        if (lane < 16)
            P1[(size_t)g * (8 * PW) + (size_t)(2 * tm + wr) * PW + tn * 128 + wc * 64 + j * 16 + lane] = cacc;
    }
}

// ---------- Legacy fused GEMM (slow/fallback path, f32 K into out) ----------
__global__ __launch_bounds__(256)
void gt_gemm_legacy(const float* __restrict__ tra, const float* __restrict__ det,
                    const float* __restrict__ eps,
                    float* __restrict__ Koutf, float* __restrict__ P1)
{
    __shared__ short As[128 * 40];
    __shared__ short Bs[128 * 40];
    __shared__ float rnA[128];
    __shared__ float rnB[128];
    int bid = blockIdx.x;
    int xcd = bid & 7, slot = bid >> 3;
    int g = xcd * 16 + (slot >> 4);
    int tile = slot & 15;
    int tm = tile >> 2, tn = tile & 3;
    int t = threadIdx.x, lane = t & 63, wave = t >> 6;
    int wr = wave >> 1, wc = wave & 1;
    f32x4 acc[4][4] = {};
    const float* Abase = tra + (size_t)g * MDIM * DDIM + (size_t)(tm * 128) * DDIM;
    const float* Bbase = det + (size_t)g * NDIM * DDIM + (size_t)(tn * 128) * DDIM;
    int srow = t >> 3, scol = t & 7;
    float ssA[4] = {0.f, 0.f, 0.f, 0.f};
    float ssB[4] = {0.f, 0.f, 0.f, 0.f};

    for (int kt = 0; kt < 16; ++kt) {
        int k0 = kt * 32;
        #pragma unroll
        for (int p = 0; p < 4; ++p) {
            int row = p * 32 + srow;
            float4 a = *reinterpret_cast<const float4*>(Abase + (size_t)row * DDIM + k0 + scol * 4);
            float4 b = *reinterpret_cast<const float4*>(Bbase + (size_t)row * DDIM + k0 + scol * 4);
            ssA[p] += a.x*a.x + a.y*a.y + a.z*a.z + a.w*a.w;
            ssB[p] += b.x*b.x + b.y*b.y + b.z*b.z + b.w*b.w;
            *reinterpret_cast<short4v*>(&As[row * 40 + scol * 4]) = cvt4(a);
            *reinterpret_cast<short4v*>(&Bs[row * 40 + scol * 4]) = cvt4(b);
        }
        __syncthreads();
        short8 af[4], bfv[4];
        #pragma unroll
        for (int i = 0; i < 4; ++i) {
            int arow = wr * 64 + i * 16 + (lane & 15);
            af[i]  = *reinterpret_cast<const short8*>(&As[arow * 40 + (lane >> 4) * 8]);
            int brow = wc * 64 + i * 16 + (lane & 15);
            bfv[i] = *reinterpret_cast<const short8*>(&Bs[brow * 40 + (lane >> 4) * 8]);
        }
        #pragma unroll
        for (int i = 0; i < 4; ++i)
            #pragma unroll
            for (int j = 0; j < 4; ++j)
                acc[i][j] = __builtin_amdgcn_mfma_f32_16x16x32_bf16(af[i], bfv[j], acc[i][j], 0, 0, 0);
        __syncthreads();
    }

    #pragma unroll
    for (int p = 0; p < 4; ++p) {
        float a = ssA[p], b = ssB[p];
        a += __shfl_xor(a, 1); a += __shfl_xor(a, 2); a += __shfl_xor(a, 4);
        b += __shfl_xor(b, 1); b += __shfl_xor(b, 2); b += __shfl_xor(b, 4);
        if (scol == 0) { rnA[p * 32 + srow] = rsqrtf(a); rnB[p * 32 + srow] = rsqrtf(b); }
    }
    __syncthreads();

    float lam = __expf(eps[0]) + 0.03f;
    float nscale = -1.0f / lam;
    size_t obase = (size_t)g * 263169;
    int r0v = (lane >> 4) * 4;
    int c0 = lane & 15;
    #pragma unroll
    for (int j = 0; j < 4; ++j) {
        int lcol = wc * 64 + j * 16 + c0;
        int colg = tn * 128 + lcol;
        float sc2 = nscale * rnB[lcol];
        float cacc = 0.f;
        #pragma unroll
        for (int i = 0; i < 4; ++i) {
            int lrow = wr * 64 + i * 16 + r0v;
            #pragma unroll
            for (int r = 0; r < 4; ++r) {
                float ev = __expf(acc[i][j][r] * rnA[lrow + r] * sc2);
                cacc += ev;
                int rowg = tm * 128 + lrow + r;
                Koutf[obase + (size_t)rowg * 513 + colg] = ev;
            }
        }
        cacc += __shfl_down(cacc, 32);
        cacc += __shfl_down(cacc, 16);
        if (lane < 16)
            P1[(size_t)g * (8 * PW) + (size_t)(2 * tm + wr) * PW + tn * 128 + wc * 64 + j * 16 + lane] = cacc;
    }
}

// ---------- Kernel 2 (x8): fused iteration, 512 threads (8 waves, 8 rows/wave) ----------
// FP8=true: K is fp8 e4m3, 512 B/row. FP8=false: f32 [513]-stride K in d_out (fallback).
// LAST=true: writes the final transport plan rows directly instead of partial colsums.
template<bool FP8, bool LAST>
__global__ __launch_bounds__(512)
void gt_iter(const void* __restrict__ Kv,
             const float* __restrict__ alpha, const float* __restrict__ eps,
             const float* __restrict__ Pread, float* __restrict__ Pwrite,
             float* __restrict__ outp, int first, int writeP)
{
    __shared__ float bv_s[512];
    __shared__ float colpart[8][512];
    __shared__ float rtmp[8];
    __shared__ float scal[2];
    int g = blockIdx.y, rb = blockIdx.x;
    int t = threadIdx.x, lane = t & 63, wv = t >> 6;
    float lam = __expf(eps[0]) + 0.03f;
    float val = __expf(-alpha[0] / lam);
    const float* Pg = Pread + (size_t)g * (8 * PW);
    float au512p = first ? 1.0f : Pg[513];
    // head: one column per thread
    float cs = 0.f;
    #pragma unroll
    for (int b = 0; b < 8; ++b) cs += Pg[b * PW + t];
    float bvt = NORMC / (cs + val * au512p);
    bv_s[t] = bvt;
    float sb = bvt;
    #pragma unroll
    for (int off = 1; off < 64; off <<= 1) sb += __shfl_xor(sb, off);
    if (lane == 0) rtmp[wv] = sb;
    __syncthreads();
    if (t == 0) {
        float S_bv = 0.f;
        #pragma unroll
        for (int w = 0; w < 8; ++w) S_bv += rtmp[w];
        float S_au_prev;
        if (first) S_au_prev = 513.f;
        else { float s = 0.f; for (int b = 0; b < 8; ++b) s += Pg[b * PW + 512]; S_au_prev = s + au512p; }
        float bv512 = BINW / (val * S_au_prev);
        float au512n = BINW / (val * (S_bv + bv512));
        scal[0] = bv512;
        scal[1] = au512n;
        if (!LAST && rb == 0) Pwrite[(size_t)g * (8 * PW) + 513] = au512n;
    }
    __syncthreads();
    float bv512 = scal[0];

    float bvr[8];
    #pragma unroll
    for (int k = 0; k < 8; ++k) bvr[k] = bv_s[lane * 8 + k];
    float colacc[8] = {};
    float suma = 0.f;
    size_t base = FP8 ? ((size_t)g << 18) : ((size_t)g * 263169);
    size_t obase = (size_t)g * 263169;
    int rowbase = rb * 64;
    for (int rr = wv; rr < 64; rr += 8) {
        int r = rowbase + rr;
        float kv[8];
        if constexpr (FP8) {
            uint2 w = *reinterpret_cast<const uint2*>((const unsigned char*)Kv + base + (size_t)r * 512 + lane * 8);
            kv[0] = e4m32f(w.x & 255u);
            kv[1] = e4m32f((w.x >> 8) & 255u);
            kv[2] = e4m32f((w.x >> 16) & 255u);
            kv[3] = e4m32f(w.x >> 24);
            kv[4] = e4m32f(w.y & 255u);
            kv[5] = e4m32f((w.y >> 8) & 255u);
            kv[6] = e4m32f((w.y >> 16) & 255u);
            kv[7] = e4m32f(w.y >> 24);
        } else {
            const float* p = (const float*)Kv + base + (size_t)r * 513 + lane * 8;
            #pragma unroll
            for (int k = 0; k < 8; ++k) kv[k] = p[k];
        }
        float dot = 0.f;
        #pragma unroll
        for (int k = 0; k < 8; ++k) dot += kv[k] * bvr[k];
        #pragma unroll
        for (int off = 1; off < 64; off <<= 1) dot += __shfl_xor(dot, off);
        float au_r = NORMC / (dot + val * bv512);
        if constexpr (LAST) {
            float* orow = outp + obase + (size_t)r * 513;
            f32x4 o0, o1;
            #pragma unroll
            for (int k = 0; k < 4; ++k) {
                o0[k] = kv[k] * au_r * bvr[k];
                o1[k] = kv[4 + k] * au_r * bvr[4 + k];
            }
            *reinterpret_cast<f32x4*>(orow + lane * 8)     = o0;
            *reinterpret_cast<f32x4*>(orow + lane * 8 + 4) = o1;
            if (lane == 0) orow[512] = val * au_r * bv512;
        } else {
            suma += au_r;
            #pragma unroll
            for (int k = 0; k < 8; ++k) colacc[k] += kv[k] * au_r;
        }
    }
    if constexpr (LAST) {
        if (rb == 7) {
            float au512n = scal[1];
            float* brow = outp + obase + (size_t)512 * 513;
            brow[t] = val * au512n * bv_s[t];
            if (t == 0) brow[512] = val * au512n * bv512;
        }
    } else if (writeP) {
        #pragma unroll
        for (int k = 0; k < 8; ++k) colpart[wv][lane * 8 + k] = colacc[k];
        if (lane == 0) rtmp[wv] = suma;
        __syncthreads();
        float s0 = 0.f;
        #pragma unroll
        for (int w = 0; w < 8; ++w) s0 += colpart[w][t];
        float* Pw = Pwrite + (size_t)g * (8 * PW) + (size_t)rb * PW;
        Pw[t] = s0;
        if (t == 0) {
            float ss = 0.f;
            #pragma unroll
            for (int w = 0; w < 8; ++w) ss += rtmp[w];
            Pw[512] = ss;
        }
    }
}

extern "C" void kernel_launch(void* const* d_in, const int* in_sizes, int n_in,
                              void* d_out, int out_size, void* d_ws, size_t ws_size,
                              hipStream_t stream) {
    const float* det   = (const float*)d_in[0];
    const float* tra   = (const float*)d_in[1];
    const float* alpha = (const float*)d_in[2];
    const float* eps   = (const float*)d_in[3];
    float* out = (float*)d_out;

    float* P0 = (float*)d_ws;                       // G*8*PW f32
    float* P1 = P0 + (size_t)G * 8 * PW;            // G*8*PW f32
    unsigned char* ke = (unsigned char*)(P1 + (size_t)G * 8 * PW);   // G*512*512 fp8

    size_t smallBytes = (size_t)2 * G * 8 * PW * 4;
    bool fast = ws_size >= smallBytes + ((size_t)G << 18);

    if (fast) {
        // bf16 normalized inputs staged in d_out (fully overwritten by the last iter)
        unsigned short* trab = (unsigned short*)out;
        unsigned short* detb = trab + ((size_t)G << 18);
        gt_cvt_kernel<<<(2 * G * MDIM) / 8, 256, 0, stream>>>(tra, det, trab, detb);
        gt_gemm_bf16<<<2048, 256, 0, stream>>>(trab, detb, eps, ke, P1);
        float* Pr = P1; float* Pw = P0;
        for (int it = 0; it < 7; ++it) {
            gt_iter<true, false><<<dim3(8, G), 512, 0, stream>>>((const void*)ke, alpha, eps, Pr, Pw, nullptr, it == 0 ? 1 : 0, 1);
            float* tmp = Pr; Pr = Pw; Pw = tmp;
        }
        gt_iter<true, true><<<dim3(8, G), 512, 0, stream>>>((const void*)ke, alpha, eps, Pr, Pw, out, 0, 0);
    } else {
        gt_gemm_legacy<<<2048, 256, 0, stream>>>(tra, det, eps, out, P1);
        float* Pr = P1; float* Pw = P0;
        for (int it = 0; it < 7; ++it) {
            gt_iter<false, false><<<dim3(8, G), 512, 0, stream>>>((const void*)out, alpha, eps, Pr, Pw, nullptr, it == 0 ? 1 : 0, 1);
            float* tmp = Pr; Pr = Pw; Pw = tmp;
        }
        gt_iter<false, true><<<dim3(8, G), 512, 0, stream>>>((const void*)out, alpha, eps, Pr, Pw, out, 0, 0);
    }
}